// Round 1
// baseline (340.942 us; speedup 1.0000x reference)
//
#include <hip/hip_runtime.h>
#include <hip/hip_bf16.h>
#include <math.h>

// Problem constants (from reference): B=64, C=271, S=512, O=512, K=32.
//
// Decomposition:
//   att logits: L[o,c] = sum_t G[o,t] * u[c,t], t in [0,128)
//     G[o, 0: 32] = sum_j ff[o,i,j,0]   (i = t%32)
//     G[o,32: 64] = sum_i ff[o,i,j,1]   (j = t%32)
//     G[o,64: 96] = sum_j ff[o,i,j,2]
//     G[o,96:128] = sum_i ff[o,i,j,3]
//     u[c, t] = sin/cos(pos[c,d] * 2*pi*k/32), k=t%32, d=(t/32)&1, sin if t<64
//   att = softmax over o (per column c)
//   y[b,c,q]  = sum_s x[b,c,s] * att[s,q]
//   out[b,p,q] = sum_c w[p,c] * y[b,c,q] + bias[p]   (since sum_s att[s,q] == 1)

#define BM 64
#define BN 64
#define BKD 16

// Generic batched fp32 GEMM: C[b] = A[b] (MxK, lda) * B[b] (KxN, ldb) [+ bias per row]
__global__ __launch_bounds__(256) void gemm_f32(
    const float* __restrict__ A, int lda, long sA,
    const float* __restrict__ B, int ldb, long sB,
    float* __restrict__ C, int ldc, long sC,
    int M, int N, int Kd, const float* __restrict__ bias)
{
    const int bz = blockIdx.z;
    A += (long)bz * sA;
    B += (long)bz * sB;
    C += (long)bz * sC;

    const int row0 = blockIdx.y * BM;
    const int col0 = blockIdx.x * BN;

    __shared__ float As[BKD][BM];  // As[k][m]
    __shared__ float Bs[BKD][BN];  // Bs[k][n]

    const int t = threadIdx.x;          // 0..255
    const int tx = t & 15;              // 0..15 (n groups)
    const int ty = t >> 4;              // 0..15 (m groups)

    float acc[4][4];
    #pragma unroll
    for (int i = 0; i < 4; ++i)
        #pragma unroll
        for (int j = 0; j < 4; ++j) acc[i][j] = 0.f;

    for (int k0 = 0; k0 < Kd; k0 += BKD) {
        // ---- load A tile (BM x BKD): each thread 4 consecutive k of one row
        {
            const int m  = t >> 2;            // t*4/16
            const int kk = (t & 3) * 4;       // (t*4)%16
            const int gm = row0 + m;
            #pragma unroll
            for (int i = 0; i < 4; ++i) {
                const int gk = k0 + kk + i;
                float v = 0.f;
                if (gm < M && gk < Kd) v = A[(long)gm * lda + gk];
                As[kk + i][m] = v;
            }
        }
        // ---- load B tile (BKD x BN): each thread 4 consecutive n of one k-row
        {
            const int kk = t >> 4;            // t*4/64
            const int n  = (t & 15) * 4;      // (t*4)%64
            const int gk = k0 + kk;
            #pragma unroll
            for (int i = 0; i < 4; ++i) {
                const int gn = col0 + n + i;
                float v = 0.f;
                if (gk < Kd && gn < N) v = B[(long)gk * ldb + gn];
                Bs[kk][n + i] = v;
            }
        }
        __syncthreads();

        #pragma unroll
        for (int k = 0; k < BKD; ++k) {
            float a[4], bb[4];
            #pragma unroll
            for (int i = 0; i < 4; ++i) a[i] = As[k][ty * 4 + i];
            #pragma unroll
            for (int j = 0; j < 4; ++j) bb[j] = Bs[k][tx * 4 + j];
            #pragma unroll
            for (int i = 0; i < 4; ++i)
                #pragma unroll
                for (int j = 0; j < 4; ++j)
                    acc[i][j] += a[i] * bb[j];
        }
        __syncthreads();
    }

    #pragma unroll
    for (int i = 0; i < 4; ++i) {
        const int gm = row0 + ty * 4 + i;
        if (gm >= M) continue;
        const float bv = bias ? bias[gm] : 0.f;
        #pragma unroll
        for (int j = 0; j < 4; ++j) {
            const int gn = col0 + tx * 4 + j;
            if (gn < N) C[(long)gm * ldc + gn] = acc[i][j] + bv;
        }
    }
}

// G[o, t] row/col sums of fourier_features. grid = O blocks, 128 threads.
__global__ void reduce_ff(const float* __restrict__ ff, float* __restrict__ G)
{
    const int o = blockIdx.x;
    const int t = threadIdx.x;          // 0..127
    const int g = t >> 5;               // which of the 4 channels
    const int idx = t & 31;
    const float* base = ff + (long)o * 32 * 32 * 4;
    float s = 0.f;
    if (g == 0 || g == 2) {
        const int w = (g == 0) ? 0 : 2;
        #pragma unroll 4
        for (int j = 0; j < 32; ++j) s += base[(idx * 32 + j) * 4 + w];
    } else {
        const int w = (g == 1) ? 1 : 3;
        #pragma unroll 4
        for (int i = 0; i < 32; ++i) s += base[(i * 32 + idx) * 4 + w];
    }
    G[o * 128 + t] = s;
}

// uT[t, c] = sin/cos basis, stored transposed [128, C] for the GEMM B-operand.
__global__ void basis_uT(const float* __restrict__ sp, float* __restrict__ uT, int Cn)
{
    const int idx = blockIdx.x * blockDim.x + threadIdx.x;
    if (idx >= 128 * Cn) return;
    const int t = idx / Cn;
    const int c = idx - t * Cn;
    const int g = t >> 5;
    const int k = t & 31;
    const float f = 6.283185307179586477f * (float)k / 32.0f;
    const float p = sp[c * 2 + (g & 1)];
    const float ang = p * f;
    uT[idx] = (g < 2) ? sinf(ang) : cosf(ang);
}

// softmax over o (rows) for each column c. grid = C blocks, 64 threads (1 wave).
__global__ void softmax_col(float* __restrict__ att, int O, int Cn)
{
    const int c = blockIdx.x;
    const int lane = threadIdx.x;       // 0..63
    float vals[8];
    float m = -INFINITY;
    #pragma unroll
    for (int i = 0; i < 8; ++i) {
        const int o = lane + i * 64;
        vals[i] = (o < O) ? att[(long)o * Cn + c] : -INFINITY;
        m = fmaxf(m, vals[i]);
    }
    #pragma unroll
    for (int off = 32; off; off >>= 1) m = fmaxf(m, __shfl_xor(m, off));
    float s = 0.f;
    #pragma unroll
    for (int i = 0; i < 8; ++i) {
        vals[i] = expf(vals[i] - m);
        s += vals[i];
    }
    #pragma unroll
    for (int off = 32; off; off >>= 1) s += __shfl_xor(s, off);
    const float inv = 1.f / s;
    #pragma unroll
    for (int i = 0; i < 8; ++i) {
        const int o = lane + i * 64;
        if (o < O) att[(long)o * Cn + c] = vals[i] * inv;
    }
}

extern "C" void kernel_launch(void* const* d_in, const int* in_sizes, int n_in,
                              void* d_out, int out_size, void* d_ws, size_t ws_size,
                              hipStream_t stream)
{
    const float* x  = (const float*)d_in[0];  // [B,C,S]
    const float* ff = (const float*)d_in[1];  // [O,32,32,4]
    const float* sp = (const float*)d_in[2];  // [C,2]
    const float* pw = (const float*)d_in[3];  // [O,C]
    const float* pb = (const float*)d_in[4];  // [O]
    float* out = (float*)d_out;               // [B,O,C]

    const int B = 64, C = 271, S = 512, O = 512;

    float* ws  = (float*)d_ws;
    float* G   = ws;                    // 512*128      = 65536
    float* uT  = G + 512 * 128;         // 128*271      = 34688
    float* att = uT + 128 * C;          // 512*271      = 138752
    float* y   = att + 512 * C;         // 64*271*271   = 4700224
    // total ~18.9 MB of workspace

    // 1) G from fourier features
    reduce_ff<<<O, 128, 0, stream>>>(ff, G);

    // 2) sin/cos basis (transposed)
    {
        const int total = 128 * C;
        basis_uT<<<(total + 255) / 256, 256, 0, stream>>>(sp, uT, C);
    }

    // 3) attention logits: att[O,C] = G[O,128] * uT[128,C]
    gemm_f32<<<dim3((C + BN - 1) / BN, (O + BM - 1) / BM, 1), 256, 0, stream>>>(
        G, 128, 0, uT, C, 0, att, C, 0, O, C, 128, nullptr);

    // 4) softmax over o per column
    softmax_col<<<C, 64, 0, stream>>>(att, O, C);

    // 5) y[b] = x[b] (C x S) * att (S x C)
    gemm_f32<<<dim3((C + BN - 1) / BN, (C + BM - 1) / BM, B), 256, 0, stream>>>(
        x, S, (long)C * S, att, C, 0, y, C, (long)C * C, C, C, S, nullptr);

    // 6) out[b] = pw (O x C) * y[b] (C x C) + pb
    gemm_f32<<<dim3((C + BN - 1) / BN, (O + BM - 1) / BM, B), 256, 0, stream>>>(
        pw, C, 0, y, C, (long)C * C, out, C, (long)O * C, O, C, C, pb);
}

// Round 2
// 99.198 us; speedup vs baseline: 3.4370x; 3.4370x over previous
//
#include <hip/hip_runtime.h>
#include <hip/hip_bf16.h>
#include <math.h>

// B=64, C=271, S=512, O=512, K=32.
// Pipeline:
//   G[o,t]    = separable row/col sums of fourier_features      (reduce_ff)
//   uT[t,c]   = sin/cos basis                                    (basis_uT)
//   att[o,c]  = G * uT  (fp32 gemm), softmax over o              (gemm_f32, softmax_col)
//   attT_bf[q,s] = att[s,q] in bf16                              (conv_attT)
//   yT_bf[b][q,c] = (x[b] (CxS) * att (SxC))^T  via MFMA         (gemm_mfma<0,0>)
//   out[b][p,q]   = pw (OxC) * y[b] (CxC) + pb  via MFMA         (gemm_mfma<1,1>)
// K-dim (C=271) zero-padded to 288 in pw_bf / yT_bf pad region.

typedef short s16x8 __attribute__((ext_vector_type(8)));
typedef short s16x4 __attribute__((ext_vector_type(4)));
typedef float f32x4 __attribute__((ext_vector_type(4)));

__device__ __forceinline__ short f2bf(float f) {
    __hip_bfloat16 h = __float2bfloat16(f);
    return *reinterpret_cast<short*>(&h);
}

#define TILE 128
#define TK 32
#define LDSK 40   // padded k-stride in shorts: 80B, 16B-aligned

// MODE 0: store transposed bf16 (Out[gn*ldo+gm]); MODE 1: store f32 + bias (Out[gm*ldo+gn])
// ABF16: A operand is bf16 (row 16B-aligned) vs fp32
template<int MODE, int ABF16>
__global__ __launch_bounds__(256) void gemm_mfma(
    const void* __restrict__ Av, long sA, int lda, int Mvalid,
    const short* __restrict__ BT, long sBT, int ldbt, int Nvalid,
    int nk, int Kvalid,
    void* __restrict__ Out, long sOut, int ldo, int Mstore,
    const float* __restrict__ bias)
{
    const int b = blockIdx.z;
    const short* Bb = BT + (long)b * sBT;
    const int m0 = blockIdx.y * TILE;
    const int n0 = blockIdx.x * TILE;

    __shared__ short As[TILE][LDSK];
    __shared__ short Bs[TILE][LDSK];

    const int t = threadIdx.x;
    const int lane = t & 63;
    const int wid = t >> 6;
    const int wr = wid >> 1;          // 0..1
    const int wc = wid & 1;           // 0..1
    const int lr = lane & 15;
    const int lk = (lane >> 4) * 8;   // k offset within tile: 0,8,16,24

    f32x4 acc[4][4];
    #pragma unroll
    for (int i = 0; i < 4; ++i)
        #pragma unroll
        for (int j = 0; j < 4; ++j)
            acc[i][j] = (f32x4){0.f, 0.f, 0.f, 0.f};

    for (int kt = 0; kt < nk; ++kt) {
        const int k0 = kt * TK;

        // ---- stage A tile (TILE rows x TK k), 2 chunks of 8 per thread
        #pragma unroll
        for (int i = 0; i < 2; ++i) {
            const int c   = t + i * 256;
            const int row = c >> 2;
            const int kk  = (c & 3) * 8;
            const int gm  = m0 + row;
            s16x8 v = {0,0,0,0,0,0,0,0};
            if (ABF16) {
                const short* Ab = (const short*)Av + (long)b * sA;
                if (gm < Mvalid)
                    v = *(const s16x8*)&Ab[(long)gm * lda + k0 + kk];
            } else {
                const float* Af = (const float*)Av + (long)b * sA;
                if (gm < Mvalid) {
                    const float* p = &Af[(long)gm * lda + k0 + kk];
                    if (k0 + kk + 8 <= Kvalid) {
                        f32x4 u0 = *(const f32x4*)p;
                        f32x4 u1 = *(const f32x4*)(p + 4);
                        #pragma unroll
                        for (int j = 0; j < 4; ++j) { v[j] = f2bf(u0[j]); v[4 + j] = f2bf(u1[j]); }
                    } else {
                        #pragma unroll
                        for (int j = 0; j < 8; ++j) {
                            const int gk = k0 + kk + j;
                            v[j] = (gk < Kvalid) ? f2bf(p[j]) : (short)0;
                        }
                    }
                }
            }
            *(s16x8*)&As[row][kk] = v;
        }
        // ---- stage BT tile
        #pragma unroll
        for (int i = 0; i < 2; ++i) {
            const int c   = t + i * 256;
            const int row = c >> 2;
            const int kk  = (c & 3) * 8;
            const int gn  = n0 + row;
            s16x8 v = {0,0,0,0,0,0,0,0};
            if (gn < Nvalid)
                v = *(const s16x8*)&Bb[(long)gn * ldbt + k0 + kk];
            *(s16x8*)&Bs[row][kk] = v;
        }
        __syncthreads();

        s16x8 af[4], bfr[4];
        #pragma unroll
        for (int m = 0; m < 4; ++m)
            af[m] = *(const s16x8*)&As[wr * 64 + m * 16 + lr][lk];
        #pragma unroll
        for (int n = 0; n < 4; ++n)
            bfr[n] = *(const s16x8*)&Bs[wc * 64 + n * 16 + lr][lk];
        #pragma unroll
        for (int m = 0; m < 4; ++m)
            #pragma unroll
            for (int n = 0; n < 4; ++n)
                acc[m][n] = __builtin_amdgcn_mfma_f32_16x16x32_bf16(af[m], bfr[n], acc[m][n], 0, 0, 0);
        __syncthreads();
    }

    if (MODE == 0) {
        short* O = (short*)Out + (long)b * sOut;
        #pragma unroll
        for (int i = 0; i < 4; ++i) {
            const int gm = m0 + wr * 64 + i * 16 + (lane >> 4) * 4;  // 4 consecutive rows
            if (gm >= Mstore) continue;  // Mstore multiple of 4: all-or-nothing
            #pragma unroll
            for (int j = 0; j < 4; ++j) {
                const int gn = n0 + wc * 64 + j * 16 + lr;
                if (gn < Nvalid) {
                    s16x4 v;
                    #pragma unroll
                    for (int r = 0; r < 4; ++r) v[r] = f2bf(acc[i][j][r]);
                    *(s16x4*)&O[(long)gn * ldo + gm] = v;
                }
            }
        }
    } else {
        float* O = (float*)Out + (long)b * sOut;
        #pragma unroll
        for (int j = 0; j < 4; ++j) {
            const int gn = n0 + wc * 64 + j * 16 + lr;
            if (gn >= Nvalid) continue;
            #pragma unroll
            for (int i = 0; i < 4; ++i) {
                const int gmb = m0 + wr * 64 + i * 16 + (lane >> 4) * 4;
                #pragma unroll
                for (int r = 0; r < 4; ++r) {
                    const int gm = gmb + r;
                    if (gm < Mstore) O[(long)gm * ldo + gn] = acc[i][j][r] + bias[gm];
                }
            }
        }
    }
}

// ---------------- small fp32 GEMM for the attention logits ----------------
#define BM 64
#define BN 64
#define BKD 16
__global__ __launch_bounds__(256) void gemm_f32(
    const float* __restrict__ A, int lda,
    const float* __restrict__ B, int ldb,
    float* __restrict__ C, int ldc,
    int M, int N, int Kd)
{
    const int row0 = blockIdx.y * BM;
    const int col0 = blockIdx.x * BN;
    __shared__ float As[BKD][BM];
    __shared__ float Bs[BKD][BN];
    const int t = threadIdx.x;
    const int tx = t & 15;
    const int ty = t >> 4;
    float acc[4][4];
    #pragma unroll
    for (int i = 0; i < 4; ++i)
        #pragma unroll
        for (int j = 0; j < 4; ++j) acc[i][j] = 0.f;

    for (int k0 = 0; k0 < Kd; k0 += BKD) {
        {
            const int m  = t >> 2;
            const int kk = (t & 3) * 4;
            const int gm = row0 + m;
            #pragma unroll
            for (int i = 0; i < 4; ++i) {
                const int gk = k0 + kk + i;
                float v = 0.f;
                if (gm < M && gk < Kd) v = A[(long)gm * lda + gk];
                As[kk + i][m] = v;
            }
        }
        {
            const int kk = t >> 4;
            const int n  = (t & 15) * 4;
            const int gk = k0 + kk;
            #pragma unroll
            for (int i = 0; i < 4; ++i) {
                const int gn = col0 + n + i;
                float v = 0.f;
                if (gk < Kd && gn < N) v = B[(long)gk * ldb + gn];
                Bs[kk][n + i] = v;
            }
        }
        __syncthreads();
        #pragma unroll
        for (int k = 0; k < BKD; ++k) {
            float a[4], bb[4];
            #pragma unroll
            for (int i = 0; i < 4; ++i) a[i] = As[k][ty * 4 + i];
            #pragma unroll
            for (int j = 0; j < 4; ++j) bb[j] = Bs[k][tx * 4 + j];
            #pragma unroll
            for (int i = 0; i < 4; ++i)
                #pragma unroll
                for (int j = 0; j < 4; ++j) acc[i][j] += a[i] * bb[j];
        }
        __syncthreads();
    }
    #pragma unroll
    for (int i = 0; i < 4; ++i) {
        const int gm = row0 + ty * 4 + i;
        if (gm >= M) continue;
        #pragma unroll
        for (int j = 0; j < 4; ++j) {
            const int gn = col0 + tx * 4 + j;
            if (gn < N) C[(long)gm * ldc + gn] = acc[i][j];
        }
    }
}

// ---------------- helpers ----------------
__global__ void reduce_ff(const float* __restrict__ ff, float* __restrict__ G)
{
    const int o = blockIdx.x;
    const int t = threadIdx.x;          // 0..127
    const int g = t >> 5;
    const int idx = t & 31;
    const float* base = ff + (long)o * 32 * 32 * 4;
    float s = 0.f;
    if (g == 0 || g == 2) {
        const int w = (g == 0) ? 0 : 2;
        #pragma unroll 4
        for (int j = 0; j < 32; ++j) s += base[(idx * 32 + j) * 4 + w];
    } else {
        const int w = (g == 1) ? 1 : 3;
        #pragma unroll 4
        for (int i = 0; i < 32; ++i) s += base[(i * 32 + idx) * 4 + w];
    }
    G[o * 128 + t] = s;
}

__global__ void basis_uT(const float* __restrict__ sp, float* __restrict__ uT, int Cn)
{
    const int idx = blockIdx.x * blockDim.x + threadIdx.x;
    if (idx >= 128 * Cn) return;
    const int t = idx / Cn;
    const int c = idx - t * Cn;
    const int g = t >> 5;
    const int k = t & 31;
    const float f = 6.283185307179586477f * (float)k / 32.0f;
    const float p = sp[c * 2 + (g & 1)];
    const float ang = p * f;
    uT[idx] = (g < 2) ? sinf(ang) : cosf(ang);
}

__global__ void softmax_col(float* __restrict__ att, int O, int Cn)
{
    const int c = blockIdx.x;
    const int lane = threadIdx.x;       // 0..63
    float vals[8];
    float m = -INFINITY;
    #pragma unroll
    for (int i = 0; i < 8; ++i) {
        const int o = lane + i * 64;
        vals[i] = (o < O) ? att[(long)o * Cn + c] : -INFINITY;
        m = fmaxf(m, vals[i]);
    }
    #pragma unroll
    for (int off = 32; off; off >>= 1) m = fmaxf(m, __shfl_xor(m, off));
    float s = 0.f;
    #pragma unroll
    for (int i = 0; i < 8; ++i) { vals[i] = expf(vals[i] - m); s += vals[i]; }
    #pragma unroll
    for (int off = 32; off; off >>= 1) s += __shfl_xor(s, off);
    const float inv = 1.f / s;
    #pragma unroll
    for (int i = 0; i < 8; ++i) {
        const int o = lane + i * 64;
        if (o < O) att[(long)o * Cn + c] = vals[i] * inv;
    }
}

// att[s,q] f32 -> attT[q,s] bf16
__global__ void conv_attT(const float* __restrict__ att, short* __restrict__ attT, int S, int Cn)
{
    const int idx = blockIdx.x * blockDim.x + threadIdx.x;
    if (idx >= S * Cn) return;
    const int q = idx / S;
    const int s = idx - q * S;
    attT[(long)q * S + s] = f2bf(att[(long)s * Cn + q]);
}

// pw[p,c] f32 [O x C] -> pw_bf[p,k] bf16 [O x Kp] zero-padded
__global__ void conv_pw(const float* __restrict__ pw, short* __restrict__ pwb, int O, int Cn, int Kp)
{
    const int idx = blockIdx.x * blockDim.x + threadIdx.x;
    if (idx >= O * Kp) return;
    const int p = idx / Kp;
    const int k = idx - p * Kp;
    pwb[idx] = (k < Cn) ? f2bf(pw[(long)p * Cn + k]) : (short)0;
}

extern "C" void kernel_launch(void* const* d_in, const int* in_sizes, int n_in,
                              void* d_out, int out_size, void* d_ws, size_t ws_size,
                              hipStream_t stream)
{
    const float* x  = (const float*)d_in[0];  // [B,C,S]
    const float* ff = (const float*)d_in[1];  // [O,32,32,4]
    const float* sp = (const float*)d_in[2];  // [C,2]
    const float* pw = (const float*)d_in[3];  // [O,C]
    const float* pb = (const float*)d_in[4];  // [O]
    float* out = (float*)d_out;               // [B,O,C]

    const int B = 64, C = 271, S = 512, O = 512;
    const int Cp = 288;                        // C padded to multiple of 32

    float* ws   = (float*)d_ws;
    float* G    = ws;                          // 512*128
    float* uT   = G + 512 * 128;               // 128*271
    float* att  = uT + 128 * C;                // 512*271 (fp32)
    short* attT = (short*)(att + 512 * C);     // 271*512 bf16
    short* pwb  = attT + (long)C * S;          // 512*288 bf16
    short* yT   = pwb + (long)O * Cp;          // 64 * 271*288 bf16
    const long syT = (long)C * Cp;             // 78048 per batch

    // 1) G from fourier features (separable reduction)
    reduce_ff<<<O, 128, 0, stream>>>(ff, G);

    // 2) sin/cos basis (transposed)
    basis_uT<<<(128 * C + 255) / 256, 256, 0, stream>>>(sp, uT, C);

    // 3) logits att[O,C] = G[O,128] * uT[128,C]  (fp32)
    gemm_f32<<<dim3((C + BN - 1) / BN, (O + BM - 1) / BM, 1), 256, 0, stream>>>(
        G, 128, uT, C, att, C, O, C, 128);

    // 4) softmax over o per column
    softmax_col<<<C, 64, 0, stream>>>(att, O, C);

    // 5) attT bf16
    conv_attT<<<(S * C + 255) / 256, 256, 0, stream>>>(att, attT, S, C);

    // 6) pw bf16, K-padded
    conv_pw<<<(O * Cp + 255) / 256, 256, 0, stream>>>(pw, pwb, O, C, Cp);

    // 7) yT[b][q,c] = (x[b] * att)^T :  A = x[b] (fp32, 271x512), BT = attT (271x512)
    gemm_mfma<0, 0><<<dim3(3, 3, B), 256, 0, stream>>>(
        (const void*)x, (long)C * S, S, C,
        attT, 0L, S, C,
        S / TK, S,
        (void*)yT, syT, Cp, Cp, nullptr);

    // 8) out[b] = pw * y[b] + pb :  A = pwb (bf16, 512x288), BT = yT[b] (271x288)
    gemm_mfma<1, 1><<<dim3(3, 4, B), 256, 0, stream>>>(
        (const void*)pwb, 0L, Cp, O,
        yT, syT, Cp, C,
        Cp / TK, Cp,
        (void*)out, (long)O * C, C, O, pb);
}